// Round 2
// baseline (395.973 us; speedup 1.0000x reference)
//
#include <hip/hip_runtime.h>
#include <math.h>

// Problem constants (fixed by setup_inputs)
#define B   8192
#define D   512
#define E   16
#define DIN 512
#define BD  (B*D)

// One block per row b (8192 blocks x 256 threads). No workspace usage at all:
// the soft/hard averages are accumulated with device-scope atomics into the
// output tail (zeroed by a stream-ordered memset before launch).
// Phase 0: issue gate loads (x, gw-fragment, pw, bias) THEN prefetch the whole
//          32KB f row into registers. f is in flight during the entire gate phase.
// Phase 1: gate logits (LDS x broadcast, gw in regs) + top-2 softmax + g_perm.
// Phase 2: consume prefetched f from registers, quad-reduce, coalesced store.
__global__ __launch_bounds__(256, 4) void moe_main(
    const float* __restrict__ f,
    const float* __restrict__ x,
    const float* __restrict__ pw,     // [P=4, E, E] flat
    const float* __restrict__ gw,     // [E, DIN]
    const float* __restrict__ bias,   // [E]
    float*       __restrict__ y,      // [B, D]
    float*       __restrict__ tail)   // out + B*D: [soft(16), hard(16)], pre-zeroed
{
    __shared__ float4 s_x4[DIN / 4];      // 128 float4 = x row (2 KB)
    __shared__ float  s_pwm[E * E];
    __shared__ float  s_logits[E];
    __shared__ float  s_gp[E];

    const int b   = blockIdx.x;
    const int tid = threadIdx.x;
    const int e   = tid >> 4;             // expert owned by this thread's group
    const int seg = tid & 15;

    // ---- phase 0a: issue gate-side loads FIRST (oldest in vmcnt queue) ----
    float4 xv = make_float4(0.f, 0.f, 0.f, 0.f);
    if (tid < DIN / 4) xv = ((const float4*)(x + (size_t)b * DIN))[tid];

    // each thread's private gw fragment: gw[e][seg + 16k], k=0..7 (32 VGPRs)
    const float4* gw4 = (const float4*)(gw + e * DIN);
    float4 gr[8];
    #pragma unroll
    for (int k = 0; k < 8; ++k) gr[k] = gw4[seg + (k << 4)];

    const float pwm = 0.25f * (pw[tid] + pw[tid + 256] + pw[tid + 512] + pw[tid + 768]);
    const float be  = bias[e];

    // ---- phase 0b: prefetch entire f row into registers (8 x float4 = 32 KB/block)
    // No dependence on the gate -> stays in flight across all three barriers.
    const float4* f4 = (const float4*)f + (size_t)b * (D * E / 4);
    float4 fv[8];
    #pragma unroll
    for (int it = 0; it < 8; ++it) fv[it] = f4[it * 256 + tid];

    // ---- stage gate inputs to LDS (compiler waits vmcnt for x/gw/pw only) ----
    if (tid < DIN / 4) s_x4[tid] = xv;
    s_pwm[tid] = pwm;
    __syncthreads();

    // ---- gate logits: thread (e, seg), x broadcast from LDS, gw from regs ----
    {
        float acc = 0.f;
        #pragma unroll
        for (int k = 0; k < 8; ++k) {
            const float4 a = s_x4[seg + (k << 4)];
            const float4 g = gr[k];
            acc += a.x * g.x + a.y * g.y + a.z * g.z + a.w * g.w;
        }
        acc += __shfl_down(acc, 8);
        acc += __shfl_down(acc, 4);
        acc += __shfl_down(acc, 2);
        acc += __shfl_down(acc, 1);
        if (seg == 0) s_logits[e] = acc + be;
    }
    __syncthreads();

    // ---- top-2 softmax + g_perm + normalize (lanes 0..15 of wave 0) ----
    if (tid < E) {
        float v1 = -INFINITY, v2 = -INFINITY;
        int   i1 = 0,         i2 = 0;
        #pragma unroll
        for (int i = 0; i < E; ++i) {
            const float v = s_logits[i];
            if (v > v1)      { v2 = v1; i2 = i1; v1 = v; i1 = i; }
            else if (v > v2) { v2 = v;  i2 = i; }
        }
        // softmax over {v1, v2} only (others masked to -inf in reference)
        const float e2    = expf(v2 - v1);
        const float denom = 1.f + e2;
        const float g1    = 1.f / denom;
        const float g2    = e2 / denom;
        // g_perm[j] = g1*pwm[i1][j] + g2*pwm[i2][j]   (j = tid)
        float gpj = g1 * s_pwm[i1 * E + tid] + g2 * s_pwm[i2 * E + tid];
        // normalize: butterfly sum over the 16 lanes
        float ssum = gpj;
        ssum += __shfl_xor(ssum, 1);
        ssum += __shfl_xor(ssum, 2);
        ssum += __shfl_xor(ssum, 4);
        ssum += __shfl_xor(ssum, 8);
        const float gpn = gpj / ssum;
        s_gp[tid] = gpn;
        // soft/hard column means: pre-scaled by 1/B (2^-13, exact) so the
        // atomic sum IS the mean. Fire-and-forget device-scope f32 adds;
        // 8192 adds/address spread over the kernel lifetime.
        atomicAdd(&tail[tid],     gpn * (1.f / B));
        atomicAdd(&tail[E + tid], (gpn < 1e-5f) ? 0.f : (1.f / B));
    }
    __syncthreads();

    // ---- phase 2: consume prefetched f; quad of lanes computes one output d ----
    {
        const float4 gq = ((const float4*)s_gp)[tid & 3];
        float* yrow = y + (size_t)b * D;
        #pragma unroll
        for (int it = 0; it < 8; ++it) {
            const float4 v = fv[it];
            float p = v.x * gq.x + v.y * gq.y + v.z * gq.z + v.w * gq.w;
            p += __shfl_xor(p, 1);
            p += __shfl_xor(p, 2);
            if ((tid & 3) == 0) yrow[it * 64 + (tid >> 2)] = p;
        }
    }
}

extern "C" void kernel_launch(void* const* d_in, const int* in_sizes, int n_in,
                              void* d_out, int out_size, void* d_ws, size_t ws_size,
                              hipStream_t stream)
{
    const float* f    = (const float*)d_in[0];
    const float* x    = (const float*)d_in[1];
    const float* pw   = (const float*)d_in[2];
    const float* gw   = (const float*)d_in[3];
    const float* bias = (const float*)d_in[4];
    float* out  = (float*)d_out;

    // Zero the 32-float tail (soft/hard averages) — stream-ordered, capture-safe.
    hipMemsetAsync(out + BD, 0, 2 * E * sizeof(float), stream);
    moe_main<<<B, 256, 0, stream>>>(f, x, pw, gw, bias, out, out + BD);
    // d_ws intentionally untouched: no workspace usage.
    (void)d_ws; (void)ws_size;
}

// Round 3
// 379.573 us; speedup vs baseline: 1.0432x; 1.0432x over previous
//
#include <hip/hip_runtime.h>
#include <math.h>

// Problem constants (fixed by setup_inputs)
#define B   8192
#define D   512
#define E   16
#define DIN 512
#define BD  (B*D)

// One block per row b (8192 blocks x 256 threads).
// Phase 0: issue gate loads (x, gw-fragment, pw, bias) THEN prefetch the whole
//          32KB f row into registers. f is in flight during the entire gate phase.
// Phase 1: gate logits (LDS x broadcast, gw in regs) + top-2 softmax + g_perm.
// Phase 2: consume prefetched f from registers, quad-reduce, coalesced store.
// NOTE (R2 post-mortem): the 1 GiB fillBuffer dispatches in the trace are
// unconditional harness workspace poison — present even with d_ws untouched.
// Atomic-tail accumulation into the output (R2) cost +15 µs vs the moe_avg
// kernel (cross-XCD atomic drain on the completion path + extra dispatch).
// This is the best-known structure (R1, 380.6 µs).
__global__ __launch_bounds__(256, 4) void moe_main(
    const float* __restrict__ f,
    const float* __restrict__ x,
    const float* __restrict__ pw,     // [P=4, E, E] flat
    const float* __restrict__ gw,     // [E, DIN]
    const float* __restrict__ bias,   // [E]
    float*       __restrict__ y,      // [B, D]
    float*       __restrict__ ws_g)   // [B, E] row-contiguous g_perm for avg kernel
{
    __shared__ float4 s_x4[DIN / 4];      // 128 float4 = x row (2 KB)
    __shared__ float  s_pwm[E * E];
    __shared__ float  s_logits[E];
    __shared__ float  s_gp[E];

    const int b   = blockIdx.x;
    const int tid = threadIdx.x;
    const int e   = tid >> 4;             // expert owned by this thread's group
    const int seg = tid & 15;

    // ---- phase 0a: issue gate-side loads FIRST (oldest in vmcnt queue) ----
    float4 xv = make_float4(0.f, 0.f, 0.f, 0.f);
    if (tid < DIN / 4) xv = ((const float4*)(x + (size_t)b * DIN))[tid];

    // each thread's private gw fragment: gw[e][seg + 16k], k=0..7 (32 VGPRs)
    const float4* gw4 = (const float4*)(gw + e * DIN);
    float4 gr[8];
    #pragma unroll
    for (int k = 0; k < 8; ++k) gr[k] = gw4[seg + (k << 4)];

    const float pwm = 0.25f * (pw[tid] + pw[tid + 256] + pw[tid + 512] + pw[tid + 768]);
    const float be  = bias[e];

    // ---- phase 0b: prefetch entire f row into registers (8 x float4 = 32 KB/block)
    // No dependence on the gate -> stays in flight across all three barriers.
    const float4* f4 = (const float4*)f + (size_t)b * (D * E / 4);
    float4 fv[8];
    #pragma unroll
    for (int it = 0; it < 8; ++it) fv[it] = f4[it * 256 + tid];

    // ---- stage gate inputs to LDS (compiler waits vmcnt for x/gw/pw only) ----
    if (tid < DIN / 4) s_x4[tid] = xv;
    s_pwm[tid] = pwm;
    __syncthreads();

    // ---- gate logits: thread (e, seg), x broadcast from LDS, gw from regs ----
    {
        float acc = 0.f;
        #pragma unroll
        for (int k = 0; k < 8; ++k) {
            const float4 a = s_x4[seg + (k << 4)];
            const float4 g = gr[k];
            acc += a.x * g.x + a.y * g.y + a.z * g.z + a.w * g.w;
        }
        acc += __shfl_down(acc, 8);
        acc += __shfl_down(acc, 4);
        acc += __shfl_down(acc, 2);
        acc += __shfl_down(acc, 1);
        if (seg == 0) s_logits[e] = acc + be;
    }
    __syncthreads();

    // ---- top-2 softmax + g_perm + normalize (lanes 0..15 of wave 0) ----
    if (tid < E) {
        float v1 = -INFINITY, v2 = -INFINITY;
        int   i1 = 0,         i2 = 0;
        #pragma unroll
        for (int i = 0; i < E; ++i) {
            const float v = s_logits[i];
            if (v > v1)      { v2 = v1; i2 = i1; v1 = v; i1 = i; }
            else if (v > v2) { v2 = v;  i2 = i; }
        }
        // softmax over {v1, v2} only (others masked to -inf in reference)
        const float e2    = expf(v2 - v1);
        const float denom = 1.f + e2;
        const float g1    = 1.f / denom;
        const float g2    = e2 / denom;
        // g_perm[j] = g1*pwm[i1][j] + g2*pwm[i2][j]   (j = tid)
        float gpj = g1 * s_pwm[i1 * E + tid] + g2 * s_pwm[i2 * E + tid];
        // normalize: butterfly sum over the 16 lanes
        float ssum = gpj;
        ssum += __shfl_xor(ssum, 1);
        ssum += __shfl_xor(ssum, 2);
        ssum += __shfl_xor(ssum, 4);
        ssum += __shfl_xor(ssum, 8);
        const float gpn = gpj / ssum;
        s_gp[tid] = gpn;
        ws_g[b * E + tid] = gpn;   // one coalesced 64B line per block
    }
    __syncthreads();

    // ---- phase 2: consume prefetched f; quad of lanes computes one output d ----
    {
        const float4 gq = ((const float4*)s_gp)[tid & 3];
        float* yrow = y + (size_t)b * D;
        #pragma unroll
        for (int it = 0; it < 8; ++it) {
            const float4 v = fv[it];
            float p = v.x * gq.x + v.y * gq.y + v.z * gq.z + v.w * gq.w;
            p += __shfl_xor(p, 1);
            p += __shfl_xor(p, 2);
            if ((tid & 3) == 0) yrow[it * 64 + (tid >> 2)] = p;
        }
    }
}

// Column means over ws_g [B, E]: soft = mean(g_perm), hard = mean(g_perm >= 1e-5).
// 16 blocks (one per expert); stride-16 gathers, all L2/L3-resident (512 KB total).
__global__ __launch_bounds__(256) void moe_avg(
    const float* __restrict__ ws_g,
    float*       __restrict__ out_tail)   // out + B*D: [soft(16), hard(16)]
{
    const int e   = blockIdx.x;
    const int tid = threadIdx.x;

    float ssum = 0.f, hsum = 0.f;
    #pragma unroll 4
    for (int i = tid; i < B; i += 256) {
        const float v = ws_g[i * E + e];
        ssum += v;
        hsum += (v < 1e-5f) ? 0.f : 1.f;   // 1 - where(gp < 1e-5, 1, 0)
    }
    // wave reduce
    #pragma unroll
    for (int off = 32; off >= 1; off >>= 1) {
        ssum += __shfl_down(ssum, off);
        hsum += __shfl_down(hsum, off);
    }
    __shared__ float s_s[4], s_h[4];
    if ((tid & 63) == 0) { s_s[tid >> 6] = ssum; s_h[tid >> 6] = hsum; }
    __syncthreads();
    if (tid == 0) {
        const float S = s_s[0] + s_s[1] + s_s[2] + s_s[3];
        const float H = s_h[0] + s_h[1] + s_h[2] + s_h[3];
        out_tail[e]     = S * (1.f / B);
        out_tail[E + e] = H * (1.f / B);
    }
}

extern "C" void kernel_launch(void* const* d_in, const int* in_sizes, int n_in,
                              void* d_out, int out_size, void* d_ws, size_t ws_size,
                              hipStream_t stream)
{
    const float* f    = (const float*)d_in[0];
    const float* x    = (const float*)d_in[1];
    const float* pw   = (const float*)d_in[2];
    const float* gw   = (const float*)d_in[3];
    const float* bias = (const float*)d_in[4];
    float* out  = (float*)d_out;
    float* ws_g = (float*)d_ws;   // needs B*E*4 = 512 KB

    moe_main<<<B, 256, 0, stream>>>(f, x, pw, gw, bias, out, ws_g);
    moe_avg<<<E, 256, 0, stream>>>(ws_g, out + BD);
}